// Round 4
// baseline (183.351 us; speedup 1.0000x reference)
//
#include <hip/hip_runtime.h>

#define ALPHA 8.3f
#define CIN   64
#define COUT  64
#define HH    128
#define WWD   128
#define NB    8

typedef __attribute__((ext_vector_type(8))) short bf16x8;   // 8 bf16 = 4 VGPRs
typedef __attribute__((ext_vector_type(4))) float f32x4;

// LDS image tile: [4 planes][130 w_idx][64 c] bf16, XOR-swizzled.
// byte = ((r*130 + wi)*64 + c)*2  ^  ((wi&7)<<4)
#define LDS_BYTES (4 * 130 * 64 * 2)

__device__ __forceinline__ unsigned lds_off(int r, int wi, int c) {
    unsigned off = (unsigned)((r * 130 + wi) * 64 + c) * 2u;
    return off ^ ((unsigned)(wi & 7) << 4);
}

__device__ __forceinline__ unsigned short f2bf(float f) {
    union { float f; unsigned u; } v; v.f = f;
    unsigned u = v.u;
    return (unsigned short)((u + 0x7FFFu + ((u >> 16) & 1u)) >> 16);  // RTN-even
}

// weight[o][c][i][j] fp32  ->  wbf[t][o][c] bf16   (t = i*3+j), 36864 elems
__global__ __launch_bounds__(256)
void wconv_kernel(const float* __restrict__ w, unsigned short* __restrict__ wbf) {
    int idx = blockIdx.x * 256 + threadIdx.x;
    if (idx >= 9 * COUT * CIN) return;
    int t   = idx / (COUT * CIN);
    int rem = idx - t * COUT * CIN;
    int o = rem >> 6, c = rem & 63;
    wbf[idx] = f2bf(w[(o * CIN + c) * 9 + t]);
}

// One block per (b, h-pair). 512 threads = 8 waves.
// Waves 0-3: row h0, positions [wv*32, wv*32+32). Waves 4-7: row h0+1.
__global__ __launch_bounds__(512, 4)
void depthconv_mfma(const float* __restrict__ img,
                    const float* __restrict__ depth,
                    const unsigned short* __restrict__ wbf,
                    const float* __restrict__ bias,
                    float* __restrict__ out)
{
    __shared__ __align__(16) char smem[LDS_BYTES];

    const int b  = blockIdx.x >> 6;
    const int h0 = (blockIdx.x & 63) * 2;
    const int tid = threadIdx.x;

    // ---- stage img rows h0-1 .. h0+2 as bf16 into LDS (zero-filled pads) ----
    const float* ib = img + b * CIN * HH * WWD;
    for (int e = tid; e < 4 * 130 * 32; e += 512) {
        int tmp = e / 130;          // (r, c2)
        int wi  = e - tmp * 130;    // 0..129 -> w = wi-1
        int c2  = tmp & 31;         // channel pair
        int r   = tmp >> 5;         // plane 0..3 -> row h0+r-1
        int hh  = h0 + r - 1;
        int w   = wi - 1;
        float v0 = 0.f, v1 = 0.f;
        if (hh >= 0 && hh < HH && w >= 0 && w < WWD) {
            v0 = ib[((2 * c2    ) * HH + hh) * WWD + w];
            v1 = ib[((2 * c2 + 1) * HH + hh) * WWD + w];
        }
        unsigned pack = (unsigned)f2bf(v0) | ((unsigned)f2bf(v1) << 16);
        *(unsigned*)(smem + lds_off(r, wi, 2 * c2)) = pack;
    }
    __syncthreads();

    const int wv    = tid >> 6;        // wave 0..7
    const int lane  = tid & 63;
    const int h     = h0 + (wv >> 2);  // this wave's output row
    const int colq  = lane & 15;       // fragment col (N)  /  A row (M)
    const int kq    = lane >> 4;       // k-quadrant 0..3
    const int rbase = wv >> 2;         // plane of row h-1 is rbase+0

    const float* db = depth + b * HH * WWD;

    for (int nt = 0; nt < 2; ++nt) {
        const int p = (wv & 3) * 32 + nt * 16 + colq;   // this lane's position

        // depth weights for the 9 taps at position p (pads: img=0, dw moot)
        float dwv[9];
        const float dc = db[h * WWD + p];
#pragma unroll
        for (int i = 0; i < 3; ++i) {
            int hh = h + i - 1; hh = hh < 0 ? 0 : (hh > HH - 1 ? HH - 1 : hh);
#pragma unroll
            for (int j = 0; j < 3; ++j) {
                int ww = p + j - 1; ww = ww < 0 ? 0 : (ww > WWD - 1 ? WWD - 1 : ww);
                float dv = db[hh * WWD + ww];
                dwv[i * 3 + j] = __expf(-ALPHA * fabsf(dc - dv));
            }
        }

        f32x4 acc[4];
#pragma unroll
        for (int mt = 0; mt < 4; ++mt) acc[mt] = (f32x4){0.f, 0.f, 0.f, 0.f};

#pragma unroll
        for (int t = 0; t < 9; ++t) {
            const int i = t / 3, j = t % 3;
            f32x4 conv[4];
#pragma unroll
            for (int mt = 0; mt < 4; ++mt) conv[mt] = (f32x4){0.f, 0.f, 0.f, 0.f};
#pragma unroll
            for (int kst = 0; kst < 2; ++kst) {
                // B frag: col = p, k = c = kst*32 + kq*8 + e  (w_idx = p + j)
                bf16x8 bfrag = *(const bf16x8*)(smem +
                                lds_off(rbase + i, p + j, kst * 32 + kq * 8));
#pragma unroll
                for (int mt = 0; mt < 4; ++mt) {
                    // A frag: row o = mt*16 + colq, k = c
                    bf16x8 afrag = *(const bf16x8*)(wbf + t * (COUT * CIN)
                                    + (mt * 16 + colq) * CIN + kst * 32 + kq * 8);
                    conv[mt] = __builtin_amdgcn_mfma_f32_16x16x32_bf16(
                                   afrag, bfrag, conv[mt], 0, 0, 0);
                }
            }
            const float d = dwv[t];
#pragma unroll
            for (int mt = 0; mt < 4; ++mt)
#pragma unroll
                for (int rr = 0; rr < 4; ++rr)
                    acc[mt][rr] = fmaf(d, conv[mt][rr], acc[mt][rr]);
        }

        // C/D: col = lane&15 (=p), row o = mt*16 + kq*4 + rr   [m89-verified]
#pragma unroll
        for (int mt = 0; mt < 4; ++mt)
#pragma unroll
            for (int rr = 0; rr < 4; ++rr) {
                int o = mt * 16 + kq * 4 + rr;
                out[((b * COUT + o) * HH + h) * WWD + p] = acc[mt][rr] + bias[o];
            }
    }
}

extern "C" void kernel_launch(void* const* d_in, const int* in_sizes, int n_in,
                              void* d_out, int out_size, void* d_ws, size_t ws_size,
                              hipStream_t stream)
{
    const float* img    = (const float*)d_in[0];
    const float* depth  = (const float*)d_in[1];
    const float* weight = (const float*)d_in[2];
    const float* bias   = (const float*)d_in[3];
    float*       out    = (float*)d_out;
    unsigned short* wbf = (unsigned short*)d_ws;   // 9*64*64*2 = 72 KB scratch

    wconv_kernel<<<(9 * COUT * CIN + 255) / 256, 256, 0, stream>>>(weight, wbf);

    dim3 grid(NB * (HH / 2));   // 512 blocks: (b, h-pair)
    dim3 block(512);            // 8 waves
    depthconv_mfma<<<grid, block, 0, stream>>>(img, depth, wbf, bias, out);
}

// Round 5
// 161.364 us; speedup vs baseline: 1.1363x; 1.1363x over previous
//
#include <hip/hip_runtime.h>

#define ALPHA 8.3f
#define CIN   64
#define COUT  64
#define HH    128
#define WWD   128
#define NB    8
#define WP    130   // padded width: wi=0 and wi=129 are zero columns

#define IMGT_BYTES ((size_t)NB * HH * WP * CIN * 2)   // 17,039,360
#define WBF_BYTES  (9 * COUT * CIN * 2)               // 73,728

typedef __attribute__((ext_vector_type(8))) short bf16x8;   // 8 bf16 = 4 VGPRs
typedef __attribute__((ext_vector_type(4))) float f32x4;

__device__ __forceinline__ unsigned short f2bf(float f) {
    union { float f; unsigned u; } v; v.f = f;
    unsigned u = v.u;
    return (unsigned short)((u + 0x7FFFu + ((u >> 16) & 1u)) >> 16);  // RTN-even
}

// ---------------- weights: w[o][c][i][j] f32 -> wbf[t][o][c] bf16 ----------------
__global__ __launch_bounds__(256)
void wconv_kernel(const float* __restrict__ w, unsigned short* __restrict__ wbf) {
    int idx = blockIdx.x * 256 + threadIdx.x;
    if (idx >= 9 * COUT * CIN) return;
    int t   = idx / (COUT * CIN);
    int rem = idx - t * COUT * CIN;
    int o = rem >> 6, c = rem & 63;
    wbf[idx] = f2bf(w[(o * CIN + c) * 9 + t]);
}

// ---------------- transpose: img[b][c][h][w] f32 -> imgT[b][h][wi][c] bf16 -------
// One block per (b,h); b = id&7 so XCD(id%8) owns batch b (L2 affinity for conv).
__global__ __launch_bounds__(256)
void tpose_kernel(const float* __restrict__ img, unsigned short* __restrict__ imgT)
{
    __shared__ unsigned short tile[CIN][132];   // stride 132 breaks pow2 banks

    const int b = blockIdx.x & 7;
    const int h = blockIdx.x >> 3;
    const int tid = threadIdx.x;
    const int g   = tid >> 5;    // 0..7
    const int w4  = tid & 31;    // float4 index along w

    const float* src = img + ((size_t)(b * CIN) * HH + h) * WWD;
#pragma unroll
    for (int citer = 0; citer < 8; ++citer) {
        const int c = citer * 8 + g;
        const float4 v = *(const float4*)(src + (size_t)c * HH * WWD + w4 * 4);
        unsigned short u0 = f2bf(v.x), u1 = f2bf(v.y), u2 = f2bf(v.z), u3 = f2bf(v.w);
        unsigned long long pk = (unsigned long long)u0 | ((unsigned long long)u1 << 16)
                              | ((unsigned long long)u2 << 32) | ((unsigned long long)u3 << 48);
        *(unsigned long long*)&tile[c][w4 * 4] = pk;
    }
    __syncthreads();

    unsigned short* dst = imgT + ((size_t)(b * HH + h) * WP) * CIN;
    const int cg = g;            // 0..7 -> channels cg*8..cg*8+7
#pragma unroll
    for (int k = 0; k < 5; ++k) {
        const int wi = (tid & 31) + k * 32;
        if (wi < WP) {
            union { unsigned short u[8]; uint4 v; } pk;
            if (wi == 0 || wi == WP - 1) {
#pragma unroll
                for (int e = 0; e < 8; ++e) pk.u[e] = 0;
            } else {
#pragma unroll
                for (int e = 0; e < 8; ++e) pk.u[e] = tile[cg * 8 + e][wi - 1];
            }
            *(uint4*)(dst + (size_t)wi * CIN + cg * 8) = pk.v;
        }
    }
}

// ---------------- conv: LDS-free MFMA, A=img (M=p), B=weights (N=o) --------------
// Block = one (b,h) row, 4 waves, wave wv owns p in [wv*32, wv*32+32).
// D mapping (m89): col=lane&15 = o_local, row=(lane>>4)*4+rr = p offset
//   -> each lane's 4 acc regs are 4 consecutive w -> f32x4 stores.
__global__ __launch_bounds__(256, 4)
void conv2_kernel(const unsigned short* __restrict__ imgT,
                  const float* __restrict__ depth,
                  const unsigned short* __restrict__ wbf,
                  const float* __restrict__ bias,
                  float* __restrict__ out)
{
    const int b = blockIdx.x & 7;     // = XCD -> imgT[b] lives in this XCD's L2
    const int h = blockIdx.x >> 3;
    const int tid  = threadIdx.x;
    const int wv   = tid >> 6;
    const int lane = tid & 63;
    const int colq = lane & 15;       // A row sel is colq too (p = base+colq)
    const int kq   = lane >> 4;       // k-quadrant; D rows p = base+kq*4+rr
    const int p0   = wv * 32;

    // --- depth rows into registers (all-static indexing -> stays in VGPRs) ---
    const float* db = depth + (size_t)b * HH * WWD;
    float drow[2][3][6];
#pragma unroll
    for (int nt = 0; nt < 2; ++nt) {
        const int pb = p0 + nt * 16 + kq * 4;
#pragma unroll
        for (int r = 0; r < 3; ++r) {
            int hh = h + r - 1; hh = hh < 0 ? 0 : (hh > HH - 1 ? HH - 1 : hh);
#pragma unroll
            for (int k = 0; k < 6; ++k) {
                int pc = pb + k - 1; pc = pc < 0 ? 0 : (pc > WWD - 1 ? WWD - 1 : pc);
                drow[nt][r][k] = db[hh * WWD + pc];
            }
        }
    }

    f32x4 acc[2][4];
#pragma unroll
    for (int nt = 0; nt < 2; ++nt)
#pragma unroll
        for (int mt = 0; mt < 4; ++mt) acc[nt][mt] = (f32x4){0.f, 0.f, 0.f, 0.f};

#pragma unroll
    for (int i = 0; i < 3; ++i) {
        const int hh = h + i - 1;
        if (hh < 0 || hh >= HH) continue;          // wave-uniform skip (h pad)
        const unsigned short* arow = imgT + ((size_t)(b * HH + hh) * WP) * CIN;
#pragma unroll
        for (int j = 0; j < 3; ++j) {
            const int t = i * 3 + j;
            const unsigned short* wt = wbf + t * (COUT * CIN);
#pragma unroll
            for (int nt = 0; nt < 2; ++nt) {
                // A frag: rows p = p0+nt*16+colq, k = c = kst*32+kq*8+e
                const unsigned short* ap = arow + (p0 + nt * 16 + colq + j) * CIN + kq * 8;
                f32x4 conv[4];
#pragma unroll
                for (int mt = 0; mt < 4; ++mt) conv[mt] = (f32x4){0.f, 0.f, 0.f, 0.f};
#pragma unroll
                for (int kst = 0; kst < 2; ++kst) {
                    const bf16x8 A = *(const bf16x8*)(ap + kst * 32);
#pragma unroll
                    for (int mt = 0; mt < 4; ++mt) {
                        const bf16x8 B = *(const bf16x8*)(wt + (mt * 16 + colq) * CIN
                                                          + kst * 32 + kq * 8);
                        conv[mt] = __builtin_amdgcn_mfma_f32_16x16x32_bf16(A, B, conv[mt], 0, 0, 0);
                    }
                }
                // per-row depth weight: p = pb+rr; tap depth = drow[nt][i][rr+j]
#pragma unroll
                for (int rr = 0; rr < 4; ++rr) {
                    const float dw = __expf(-ALPHA * fabsf(drow[nt][1][1 + rr]
                                                         - drow[nt][i][rr + j]));
#pragma unroll
                    for (int mt = 0; mt < 4; ++mt)
                        acc[nt][mt][rr] = fmaf(dw, conv[mt][rr], acc[nt][mt][rr]);
                }
            }
        }
    }

    // --- stores: f32x4 per (nt, mt); 4 consecutive w per lane ---
#pragma unroll
    for (int mt = 0; mt < 4; ++mt) {
        const int o  = mt * 16 + colq;
        const float bo = bias[o];
#pragma unroll
        for (int nt = 0; nt < 2; ++nt) {
            f32x4 v;
#pragma unroll
            for (int rr = 0; rr < 4; ++rr) v[rr] = acc[nt][mt][rr] + bo;
            *(f32x4*)(out + (((size_t)b * COUT + o) * HH + h) * WWD
                          + p0 + nt * 16 + kq * 4) = v;
        }
    }
}

// ---------------- fallback (no-ws): plain fp32, known-correct structure ----------
__global__ __launch_bounds__(128)
void depthconv_fallback(const float* __restrict__ img, const float* __restrict__ depth,
                        const float* __restrict__ weight, const float* __restrict__ bias,
                        float* __restrict__ out)
{
    const int bh = blockIdx.x;
    const int b  = bh >> 7;
    const int h  = bh & (HH - 1);
    const int w  = threadIdx.x;

    const float* dbase = depth + (size_t)b * HH * WWD;
    const float  dc    = dbase[h * WWD + w];

    float dwm[9]; int off[9];
#pragma unroll
    for (int i = 0; i < 3; ++i) {
        const int  hh2 = h + i - 1;
        const bool hok = (hh2 >= 0) && (hh2 < HH);
        const int  hc  = hok ? hh2 : h;
#pragma unroll
        for (int j = 0; j < 3; ++j) {
            const int  ww  = w + j - 1;
            const bool wok = (ww >= 0) && (ww < WWD);
            const int  wc  = wok ? ww : w;
            const bool ok  = hok && wok;
            const float dv = ok ? dbase[hh2 * WWD + ww] : 0.f;
            dwm[i * 3 + j] = (ok ? 1.f : 0.f) * __expf(-ALPHA * fabsf(dc - dv));
            off[i * 3 + j] = hc * WWD + wc;
        }
    }
    float acc[COUT];
#pragma unroll
    for (int o = 0; o < COUT; ++o) acc[o] = 0.f;
    const float* ibase = img + (size_t)b * CIN * HH * WWD;
#pragma unroll 1
    for (int c = 0; c < CIN; ++c) {
        float v[9];
#pragma unroll
        for (int t = 0; t < 9; ++t) v[t] = ibase[(size_t)c * HH * WWD + off[t]] * dwm[t];
        const float* wc_ = weight + c * 9;
#pragma unroll
        for (int o = 0; o < COUT; ++o) {
            const float* wp = wc_ + o * (CIN * 9);
#pragma unroll
            for (int t = 0; t < 9; ++t) acc[o] = fmaf(v[t], wp[t], acc[o]);
        }
    }
#pragma unroll
    for (int o = 0; o < COUT; ++o)
        out[(((size_t)b * COUT + o) * HH + h) * WWD + w] = acc[o] + bias[o];
}

extern "C" void kernel_launch(void* const* d_in, const int* in_sizes, int n_in,
                              void* d_out, int out_size, void* d_ws, size_t ws_size,
                              hipStream_t stream)
{
    const float* img    = (const float*)d_in[0];
    const float* depth  = (const float*)d_in[1];
    const float* weight = (const float*)d_in[2];
    const float* bias   = (const float*)d_in[3];
    float*       out    = (float*)d_out;

    if (ws_size >= IMGT_BYTES + WBF_BYTES) {
        unsigned short* imgT = (unsigned short*)d_ws;
        unsigned short* wbf  = (unsigned short*)((char*)d_ws + IMGT_BYTES);

        tpose_kernel<<<NB * HH, 256, 0, stream>>>(img, imgT);
        wconv_kernel<<<(9 * COUT * CIN + 255) / 256, 256, 0, stream>>>(weight, wbf);
        conv2_kernel<<<NB * HH, 256, 0, stream>>>(imgT, depth, wbf, bias, out);
    } else {
        depthconv_fallback<<<NB * HH, WWD, 0, stream>>>(img, depth, weight, bias, out);
    }
}

// Round 7
// 125.789 us; speedup vs baseline: 1.4576x; 1.2828x over previous
//
#include <hip/hip_runtime.h>
#include <hip/hip_bf16.h>

#define ALPHA 8.3f
#define CIN   64
#define COUT  64
#define HH    128
#define WWD   128
#define NB    8
#define WP    130   // wi = w+1; columns 0 and 129 are zero pads

#define WBF_BYTES (9 * COUT * CIN * 2)

typedef __attribute__((ext_vector_type(8))) short bf16x8;   // 8 bf16 = 4 VGPRs
typedef __attribute__((ext_vector_type(4))) float f32x4;

__device__ __forceinline__ unsigned short f2bf(float f) {
    union { float f; unsigned u; } v; v.f = f;
    unsigned u = v.u;
    return (unsigned short)((u + 0x7FFFu + ((u >> 16) & 1u)) >> 16);  // RTN-even
}
__device__ __forceinline__ float bf2f(unsigned short s) {
    union { unsigned u; float f; } v; v.u = ((unsigned)s) << 16;
    return v.f;
}
__device__ __forceinline__ unsigned short f2bf_fast(float f) {
    union { __hip_bfloat16 h; unsigned short u; } c;
    c.h = __float2bfloat16(f);        // compiler emits v_cvt_pk_bf16_f32 pairs
    return c.u;
}

// LDS [3][WP][64] bf16, c-contiguous 128B rows. Swizzle permutes the eight
// 16B channel-groups within a row, keyed by (wi ^ (wi>>3))&7 so that BOTH
// the b128 frag reads (wi consecutive across lanes) and the b16 staging
// writes (wi stepping by 4 across lanes) spread over banks.
__device__ __forceinline__ unsigned lds_addr(int r, int wi, int c) {
    unsigned a = ((unsigned)((r * WP + wi) * CIN + c)) * 2u;
    unsigned s = ((((unsigned)wi ^ ((unsigned)wi >> 3)) & 7u) << 4);
    return a ^ s;
}

// ---------------- weights: w[o][c][i][j] f32 -> wbf[t][o][c] bf16 ----------------
__global__ __launch_bounds__(256)
void wconv_kernel(const float* __restrict__ w, unsigned short* __restrict__ wbf) {
    int idx = blockIdx.x * 256 + threadIdx.x;
    if (idx >= 9 * COUT * CIN) return;
    int t   = idx / (COUT * CIN);
    int rem = idx - t * COUT * CIN;
    int o = rem >> 6, c = rem & 63;
    wbf[idx] = f2bf(w[(o * CIN + c) * 9 + t]);
}

// ---------------- fused: stage->LDS, dw folded into A-frag, MFMA -----------------
// Block = (b,h): 512 threads = 8 waves = 4 p-quarters x 2 o-halves.
// Wave covers 32p x 32o. A = img (M=p, K=c), B = weights (K=c, N=o).
// D (m89): col=lane&15 = o_local, row=(lane>>4)*4+rr = p offset -> f32x4 stores.
__global__ __launch_bounds__(512, 4)
void conv_fused(const float* __restrict__ img,
                const float* __restrict__ depth,
                const unsigned short* __restrict__ wbf,
                const float* __restrict__ bias,
                float* __restrict__ out)
{
    __shared__ __align__(16) char smem[3 * WP * CIN * 2];   // 49,920 B

    const int b = blockIdx.x & 7;     // b = XCD (round-robin) -> L2 affinity
    const int h = blockIdx.x >> 3;
    const int tid  = threadIdx.x;
    const int wv   = tid >> 6;
    const int lane = tid & 63;
    const int colq = lane & 15;       // A row sel (p), B col sel (o)
    const int kq   = lane >> 4;       // k-quadrant; D rows p = kq*4+rr
    const int p0   = (wv & 3) * 32;
    const int o0   = (wv >> 2) * 32;

    // ---- early: depth taps + bias into regs (independent of LDS) ----
    const float* db = depth + (size_t)b * HH * WWD;
    float dt[2][3][3];
#pragma unroll
    for (int nt = 0; nt < 2; ++nt) {
        const int pA = p0 + nt * 16 + colq;
#pragma unroll
        for (int r = 0; r < 3; ++r) {
            int hh = h + r - 1; hh = hh < 0 ? 0 : (hh >= HH ? HH - 1 : hh);
#pragma unroll
            for (int k = 0; k < 3; ++k) {
                int pc = pA + k - 1; pc = pc < 0 ? 0 : (pc >= WWD ? WWD - 1 : pc);
                dt[nt][r][k] = db[hh * WWD + pc];   // clamped: only used where img!=0
            }
        }
    }
    float bo[2];
#pragma unroll
    for (int mt = 0; mt < 2; ++mt) bo[mt] = bias[o0 + mt * 16 + colq];

    // ---- stage img rows h-1..h+1 as bf16 into LDS (coalesced f32x4 reads) ----
    const float* ib = img + (size_t)b * CIN * HH * WWD;
#pragma unroll
    for (int it = 0; it < 12; ++it) {
        int f = tid + it * 512;          // 0..6143 = 3 rows x 64 c x 32 float4
        int q = f & 31;
        int c = (f >> 5) & 63;
        int r = f >> 11;
        int hh = h + r - 1;
        float4 v = make_float4(0.f, 0.f, 0.f, 0.f);
        if (hh >= 0 && hh < HH)
            v = *(const float4*)(ib + ((size_t)c * HH + hh) * WWD + q * 4);
        const int wib = 1 + q * 4;
        *(unsigned short*)(smem + lds_addr(r, wib + 0, c)) = f2bf_fast(v.x);
        *(unsigned short*)(smem + lds_addr(r, wib + 1, c)) = f2bf_fast(v.y);
        *(unsigned short*)(smem + lds_addr(r, wib + 2, c)) = f2bf_fast(v.z);
        *(unsigned short*)(smem + lds_addr(r, wib + 3, c)) = f2bf_fast(v.w);
    }
    if (tid < 384) {                     // zero pad columns wi=0 and wi=WP-1
        int c = tid & 63, idx = tid >> 6;
        int r = idx >> 1, wi = (idx & 1) ? (WP - 1) : 0;
        *(unsigned short*)(smem + lds_addr(r, wi, c)) = 0;
    }
    __syncthreads();

    f32x4 acc[2][2];
#pragma unroll
    for (int nt = 0; nt < 2; ++nt)
#pragma unroll
        for (int mt = 0; mt < 2; ++mt)
            acc[nt][mt] = (f32x4){bo[mt], bo[mt], bo[mt], bo[mt]};

#pragma unroll
    for (int i = 0; i < 3; ++i) {
        // hoist the 12 B-frags of this tap-row (independent 16B loads, batched)
        bf16x8 Bf[3][2][2];
#pragma unroll
        for (int j = 0; j < 3; ++j)
#pragma unroll
            for (int kst = 0; kst < 2; ++kst)
#pragma unroll
                for (int mt = 0; mt < 2; ++mt)
                    Bf[j][kst][mt] = *(const bf16x8*)(wbf
                        + (i * 3 + j) * (COUT * CIN)
                        + (o0 + mt * 16 + colq) * CIN + kst * 32 + kq * 8);

#pragma unroll
        for (int j = 0; j < 3; ++j) {
#pragma unroll
            for (int nt = 0; nt < 2; ++nt) {
                // dw for this lane's A-row p = p0+nt*16+colq, tap (i,j)
                const float dw = __expf(-ALPHA * fabsf(dt[nt][1][1] - dt[nt][i][j]));
                const int wi = p0 + nt * 16 + colq + j;   // = (p) + 1 + (j-1)
#pragma unroll
                for (int kst = 0; kst < 2; ++kst) {
                    bf16x8 A = *(const bf16x8*)(smem + lds_addr(i, wi, kst * 32 + kq * 8));
                    union { bf16x8 v; unsigned short u[8]; } ain, as;
                    ain.v = A;
#pragma unroll
                    for (int e = 0; e < 8; ++e)
                        as.u[e] = f2bf_fast(bf2f(ain.u[e]) * dw);
#pragma unroll
                    for (int mt = 0; mt < 2; ++mt)
                        acc[nt][mt] = __builtin_amdgcn_mfma_f32_16x16x32_bf16(
                                          as.v, Bf[j][kst][mt], acc[nt][mt], 0, 0, 0);
                }
            }
        }
    }

    // ---- store: f32x4; D rows = p0+nt*16+kq*4+rr (4 consecutive w) ----
#pragma unroll
    for (int mt = 0; mt < 2; ++mt) {
        const int o = o0 + mt * 16 + colq;
#pragma unroll
        for (int nt = 0; nt < 2; ++nt)
            *(f32x4*)(out + (((size_t)b * COUT + o) * HH + h) * WWD
                          + p0 + nt * 16 + kq * 4) = acc[nt][mt];
    }
}

// ---------------- fallback (tiny ws): plain fp32, known-correct ----------------
__global__ __launch_bounds__(128)
void depthconv_fallback(const float* __restrict__ img, const float* __restrict__ depth,
                        const float* __restrict__ weight, const float* __restrict__ bias,
                        float* __restrict__ out)
{
    const int bh = blockIdx.x;
    const int b  = bh >> 7;
    const int h  = bh & (HH - 1);
    const int w  = threadIdx.x;

    const float* dbase = depth + (size_t)b * HH * WWD;
    const float  dc    = dbase[h * WWD + w];

    float dwm[9]; int off[9];
#pragma unroll
    for (int i = 0; i < 3; ++i) {
        const int  hh2 = h + i - 1;
        const bool hok = (hh2 >= 0) && (hh2 < HH);
        const int  hc  = hok ? hh2 : h;
#pragma unroll
        for (int j = 0; j < 3; ++j) {
            const int  ww  = w + j - 1;
            const bool wok = (ww >= 0) && (ww < WWD);
            const int  wc  = wok ? ww : w;
            const bool ok  = hok && wok;
            const float dv = ok ? dbase[hh2 * WWD + ww] : 0.f;
            dwm[i * 3 + j] = (ok ? 1.f : 0.f) * __expf(-ALPHA * fabsf(dc - dv));
            off[i * 3 + j] = hc * WWD + wc;
        }
    }
    float acc[COUT];
#pragma unroll
    for (int o = 0; o < COUT; ++o) acc[o] = 0.f;
    const float* ibase = img + (size_t)b * CIN * HH * WWD;
#pragma unroll 1
    for (int c = 0; c < CIN; ++c) {
        float v[9];
#pragma unroll
        for (int t = 0; t < 9; ++t) v[t] = ibase[(size_t)c * HH * WWD + off[t]] * dwm[t];
        const float* wc_ = weight + c * 9;
#pragma unroll
        for (int o = 0; o < COUT; ++o) {
            const float* wp = wc_ + o * (CIN * 9);
#pragma unroll
            for (int t = 0; t < 9; ++t) acc[o] = fmaf(v[t], wp[t], acc[o]);
        }
    }
#pragma unroll
    for (int o = 0; o < COUT; ++o)
        out[(((size_t)b * COUT + o) * HH + h) * WWD + w] = acc[o] + bias[o];
}

extern "C" void kernel_launch(void* const* d_in, const int* in_sizes, int n_in,
                              void* d_out, int out_size, void* d_ws, size_t ws_size,
                              hipStream_t stream)
{
    const float* img    = (const float*)d_in[0];
    const float* depth  = (const float*)d_in[1];
    const float* weight = (const float*)d_in[2];
    const float* bias   = (const float*)d_in[3];
    float*       out    = (float*)d_out;

    if (ws_size >= (size_t)WBF_BYTES) {
        unsigned short* wbf = (unsigned short*)d_ws;
        wconv_kernel<<<(9 * COUT * CIN + 255) / 256, 256, 0, stream>>>(weight, wbf);
        conv_fused<<<NB * HH, 512, 0, stream>>>(img, depth, wbf, bias, out);
    } else {
        depthconv_fallback<<<NB * HH, WWD, 0, stream>>>(img, depth, weight, bias, out);
    }
}